// Round 13
// baseline (16164.029 us; speedup 1.0000x reference)
//
#include <hip/hip_runtime.h>

#define T_ 1024
#define H_ 400
#define G4H 1600
#define NG 8            // batch groups, 16 rows each
#define RG 16
#define NBLK 256
#define NTHR 512
#define N0 12           // L0 blocks per group (chunk-aligned unit ranges)
#define N1 20           // L1 blocks per group
#define PCH 58          // packed chunks per h row (57*7+1 units -> 58 chunks)
#define PSL 464         // packed halfs per row (58*8)
#define SLOTH (RG * PSL)        // 7424 halfs per group-slot
#define RINGH (4 * SLOTH)       // ring depth 4
#define SCOPE __HIP_MEMORY_SCOPE_AGENT

typedef float f32x4 __attribute__((ext_vector_type(4)));
typedef _Float16 h2 __attribute__((ext_vector_type(2)));
typedef _Float16 h4 __attribute__((ext_vector_type(4)));
union V4 { f32x4 f; h2 h[4]; };
union PK { f32x4 f; unsigned short u16[8]; };

// workspace: [f0: NG*1024 ints][f1: NG*1024 ints][h0 rings][h1 rings]
#define FLAG_BYTES (2 * NG * 1024 * 4)
#define WS_TOTAL (FLAG_BYTES + 2 * NG * RINGH * 2)   // 1,015,808

// LDS layouts (byte offsets into one 163,328B array)
#define SW0B 147840     // L0 weights: 140 cols x 528 halfs
#define SWD0 155264     // L0 packed dense W: 4 x 472 halfs
#define SW1B 155904     // L1 weights: 84 cols x 928 halfs
#define SMEMB 163328    // + [16][232] staging after weights (both roles)

__device__ __forceinline__ float sigmf(float x) { return 1.0f / (1.0f + __expf(-x)); }

// LLC-coherent ops (sc0 sc1) — proven cross-XCD path
__device__ __forceinline__ void cload4(f32x4& r, const void* p) {
  asm volatile("global_load_dwordx4 %0, %1, off sc0 sc1" : "=v"(r) : "v"(p) : "memory");
}
__device__ __forceinline__ void pload4(f32x4& r, const void* p) {   // immutable inputs
  asm volatile("global_load_dwordx4 %0, %1, off" : "=v"(r) : "v"(p) : "memory");
}
__device__ __forceinline__ void cstore16(void* p, f32x4 v) {
  asm volatile("global_store_dwordx4 %0, %1, off sc0 sc1" :: "v"(p), "v"(v) : "memory");
}
__device__ __forceinline__ void vwait0() {
  asm volatile("s_waitcnt vmcnt(0)" ::: "memory");
  __builtin_amdgcn_sched_barrier(0);   // rule #18
}
__device__ __forceinline__ unsigned tagof(const f32x4& r) {
  union { float f; unsigned u; } c; c.f = r[3]; return c.u >> 16;
}
__device__ __forceinline__ float dot2f(h2 a, h2 b, float c) {
#if __has_builtin(__builtin_amdgcn_fdot2)
  return __builtin_amdgcn_fdot2(a, b, c, false);
#else
  return fmaf((float)a[0], (float)b[0], fmaf((float)a[1], (float)b[1], c));
#endif
}
__device__ __forceinline__ void waitflag(const int* f, int tgt) {
  while (__hip_atomic_load(f, __ATOMIC_RELAXED, SCOPE) < tgt)
    __builtin_amdgcn_s_sleep(1);
}
__device__ __forceinline__ void publish(int* f) {
  asm volatile("s_waitcnt vmcnt(0)" ::: "memory");
  __syncthreads();
  if (threadIdx.x == 0) __hip_atomic_fetch_add(f, 1, __ATOMIC_RELAXED, SCOPE);
}

// K-chunk GEMM over 232-wide staged packed data; KS = k-split width
template<int KS>
__device__ __forceinline__ void gchunkT(float (&acc)[16][4], const _Float16* s_w, int ws,
                                        const _Float16* s_h, int k0w, int nslot, int ks, int cs)
{
  for (int i = ks; i < nslot; i += KS) {
    V4 w0, w1, w2, w3;
    const _Float16* wb = s_w + (cs * 4) * ws + k0w + i * 8;
    w0.f = *(const f32x4*)(wb);
    w1.f = *(const f32x4*)(wb + ws);
    w2.f = *(const f32x4*)(wb + 2 * ws);
    w3.f = *(const f32x4*)(wb + 3 * ws);
    #pragma unroll
    for (int r = 0; r < 16; ++r) {
      V4 hv; hv.f = *(const f32x4*)(s_h + r * 232 + i * 8);
      #pragma unroll
      for (int q = 0; q < 4; ++q) {
        acc[r][0] = dot2f(hv.h[q], w0.h[q], acc[r][0]);
        acc[r][1] = dot2f(hv.h[q], w1.h[q], acc[r][1]);
        acc[r][2] = dot2f(hv.h[q], w2.h[q], acc[r][2]);
        acc[r][3] = dot2f(hv.h[q], w3.h[q], acc[r][3]);
      }
    }
  }
}

// ------- Layer 0 (+dense for jj>=10): K = 464 packed h0(s-1) | 56 x | tag cols zero-weighted -------
__device__ void run_l0(int jj, int grp,
    const float* __restrict__ xr, const float* __restrict__ xc,
    const float* __restrict__ Wx0, const float* __restrict__ Wh0, const float* __restrict__ b0,
    const float* __restrict__ Wd, const float* __restrict__ bd,
    _Float16* __restrict__ h0g, const _Float16* __restrict__ h1g,
    float* __restrict__ out, int* f0, int* f1, unsigned char* smem)
{
  const int tid = threadIdx.x;
  _Float16* s_w  = (_Float16*)smem;            // [140][528]
  _Float16* s_h  = (_Float16*)(smem + SW0B);   // [16][232] staging / exchange / partials
  _Float16* s_wd = (_Float16*)(smem + SWD0);   // [4][472] packed dense W
  const int c0 = (jj < 10) ? 5 * jj : (jj == 10 ? 50 : 54);
  const int cn = (jj < 10) ? 5 : 4;
  const int u0 = c0 * 7;
  const int hi = (c0 + cn) * 7;
  const int nu = (hi > 400 ? 400 : hi) - u0;   // 35 / 28 / 22

  for (int idx = tid; idx < 140 * 528; idx += NTHR) {
    int col = idx / 528, k = idx - col * 528;
    int u = col >> 2, g = col & 3, uu = u0 + u;
    float v = 0.f;
    if (u < nu) {
      if (k < 464) { int c = k >> 3, j = k & 7;
        if (j < 7) { int su = c * 7 + j; if (su < 400) v = Wh0[su * G4H + g * H_ + uu]; } }
      else if (k < 520) v = Wx0[(k - 464) * G4H + g * H_ + uu];
    }
    s_w[idx] = (_Float16)v;
  }
  for (int idx = tid; idx < 4 * 472; idx += NTHR) {
    int f = idx / 472, k = idx - f * 472;
    float v = 0.f;
    if (k < 464) { int c = k >> 3, j = k & 7;
      if (j < 7) { int su = c * 7 + j; if (su < 400) v = Wd[su * 4 + f]; } }
    s_wd[idx] = (_Float16)v;
  }
  __syncthreads();

  const int cs = tid >> 3, ks = tid & 7;       // 8-way k-split, 2 rows per lane
  const int uu = u0 + cs;
  const bool act = cs < nu;
  float bi0 = 0, bi1 = 0, bi2 = 0, bi3 = 0;
  if (act) { bi0 = b0[uu]; bi1 = b0[H_ + uu]; bi2 = b0[2 * H_ + uu]; bi3 = b0[3 * H_ + uu]; }
  float cstA = 0.f, cstB = 0.f;
  const bool dblk = (jj >= 10);
  const int drb = (jj == 11) ? 8 : 0;
  const float bdv = (tid < 32) ? bd[tid & 3] : 0.f;

  const int i1 = tid + 512;
  const int r0 = tid / 58, cA = tid - 58 * r0;
  const bool v1 = i1 < 928;
  const int r1 = v1 ? i1 / 58 : 0, cB = v1 ? (i1 - 58 * (i1 / 58)) : 0;
  const bool vD0 = tid < 464;
  const int dr = vD0 ? tid / 58 : 0, dc = vD0 ? (tid - 58 * (tid / 58)) : 0;
  const bool xact = tid < 224;
  const int xrow = xact ? tid / 14 : 0, xc4 = xact ? (tid - 14 * (tid / 14)) : 0;

  for (int s = 0; s < T_; ++s) {
    const _Float16* h0p = h0g + ((s - 1) & 3) * SLOTH;
    _Float16*       h0n = h0g + (s & 3) * SLOTH;
    const _Float16* h1v = h1g + ((s - 4) & 3) * SLOTH;

    f32x4 rx;
    if (xact) {
      int kf = xc4 * 4;
      const float* p = (kf < 40) ? xr + ((grp * RG + xrow) * T_ + s) * 40 + kf
                                 : xc + ((grp * RG + xrow) * T_ + s) * 16 + (kf - 40);
      pload4(rx, p);
    }
    f32x4 rH0, rH1, rd;
    const _Float16* sH0 = h0p + r0 * PSL + cA * 8;
    const _Float16* sH1 = h0p + r1 * PSL + cB * 8;
    cload4(rH0, sH0);
    if (v1) cload4(rH1, sH1);
    const bool vD = dblk && (s >= 4) && vD0;
    const _Float16* sD = h1v + (drb + dr) * PSL + dc * 8;   // FIX: +drb
    if (vD) cload4(rd, sD);

    if (tid == 0 && s >= 4) waitflag(f1 + s - 4, N1);   // h0 slot s&3 free (4-slack)
    __syncthreads();

    const unsigned expA = (unsigned short)s;            // h0(s-1) tag
    vwait0();
    for (;;) {
      bool ok = (tagof(rH0) == expA) && (!v1 || tagof(rH1) == expA);
      if (__all(ok)) break;
      cload4(rH0, sH0); if (v1) cload4(rH1, sH1);
      vwait0();
    }

    float acc[16][4];
    #pragma unroll
    for (int r = 0; r < 16; ++r) { acc[r][0]=0; acc[r][1]=0; acc[r][2]=0; acc[r][3]=0; }

    if (cA < 29) *(f32x4*)(s_h + r0 * 232 + cA * 8) = rH0;
    if (v1 && cB < 29) *(f32x4*)(s_h + r1 * 232 + cB * 8) = rH1;
    __syncthreads();
    if (act) gchunkT<8>(acc, s_w, 528, s_h, 0, 29, ks, cs);
    __syncthreads();
    if (cA >= 29) *(f32x4*)(s_h + r0 * 232 + (cA - 29) * 8) = rH0;
    if (v1 && cB >= 29) *(f32x4*)(s_h + r1 * 232 + (cB - 29) * 8) = rH1;
    __syncthreads();
    if (act) gchunkT<8>(acc, s_w, 528, s_h, 232, 29, ks, cs);
    __syncthreads();
    if (xact) {
      h4 hv; hv[0] = (_Float16)rx[0]; hv[1] = (_Float16)rx[1];
             hv[2] = (_Float16)rx[2]; hv[3] = (_Float16)rx[3];
      *(h4*)(s_h + xrow * 232 + xc4 * 4) = hv;
    }
    __syncthreads();
    if (act) gchunkT<8>(acc, s_w, 528, s_h, 464, 7, ks, cs);

    #pragma unroll
    for (int r = 0; r < 16; ++r)
      #pragma unroll
      for (int g = 0; g < 4; ++g) {
        float v = acc[r][g];
        v += __shfl_xor(v, 1); v += __shfl_xor(v, 2); v += __shfl_xor(v, 4);
        acc[r][g] = v;
      }
    float gA0=0,gA1=0,gA2=0,gA3=0,gB0=0,gB1=0,gB2=0,gB3=0;
    #pragma unroll
    for (int r = 0; r < 16; ++r) {
      if (ks == r)     { gA0=acc[r][0]; gA1=acc[r][1]; gA2=acc[r][2]; gA3=acc[r][3]; }
      if (ks + 8 == r) { gB0=acc[r][0]; gB1=acc[r][1]; gB2=acc[r][2]; gB3=acc[r][3]; }
    }
    float hA = 0.f, hB = 0.f;
    if (act) {
      float iv = sigmf(gA0+bi0), fv = sigmf(gA1+bi1), gv = tanhf(gA2+bi2), ov = sigmf(gA3+bi3);
      cstA = fv * cstA + iv * gv; hA = ov * tanhf(cstA);
      iv = sigmf(gB0+bi0); fv = sigmf(gB1+bi1); gv = tanhf(gB2+bi2); ov = sigmf(gB3+bi3);
      cstB = fv * cstB + iv * gv; hB = ov * tanhf(cstB);
    }
    __syncthreads();                       // reuse s_h as exchange
    if (cs < 40) {
      s_h[ks * 40 + cs]       = act ? (_Float16)hA : (_Float16)0.f;
      s_h[(ks + 8) * 40 + cs] = act ? (_Float16)hB : (_Float16)0.f;
    }
    __syncthreads();
    if (tid < cn * 16) {                   // tagged chunk writers
      int row = tid & 15, ci = tid >> 4;
      PK pk;
      #pragma unroll
      for (int j = 0; j < 7; ++j) {
        int su = (c0 + ci) * 7 + j;
        _Float16 hvv = (su < u0 + nu) ? s_h[row * 40 + (su - u0)] : (_Float16)0.f;
        union { _Float16 h; unsigned short u; } cv; cv.h = hvv;
        pk.u16[j] = cv.u;
      }
      pk.u16[7] = (unsigned short)(s + 1);
      cstore16(h0n + row * PSL + (c0 + ci) * 8, pk.f);
    }
    if (dblk && s >= 4) {                  // dense for h1(s-4), 4-step slack
      const unsigned expD = (unsigned short)(s - 3);
      for (;;) {
        bool ok = !vD || (tagof(rd) == expD);
        if (__all(ok)) break;
        if (vD) cload4(rd, sD);
        vwait0();
      }
      __syncthreads();
      float* s_pd = (float*)s_h;
      if (vD) {
        V4 hv; hv.f = rd;
        float p0=0,p1=0,p2=0,p3=0;
        #pragma unroll
        for (int q = 0; q < 4; ++q) {
          h2 hp = hv.h[q];
          p0 = dot2f(hp, *(const h2*)(s_wd + 0*472 + dc*8 + 2*q), p0);
          p1 = dot2f(hp, *(const h2*)(s_wd + 1*472 + dc*8 + 2*q), p1);
          p2 = dot2f(hp, *(const h2*)(s_wd + 2*472 + dc*8 + 2*q), p2);
          p3 = dot2f(hp, *(const h2*)(s_wd + 3*472 + dc*8 + 2*q), p3);
        }
        f32x4 pv = {p0, p1, p2, p3};
        *(f32x4*)(s_pd + tid * 4) = pv;
      }
      __syncthreads();
      if (tid < 32) {
        int r8 = tid >> 2, f = tid & 3;
        float sum = bdv;
        for (int c = 0; c < 58; ++c) sum += s_pd[(r8 * 58 + c) * 4 + f];
        out[((grp * RG + drb + r8) * T_ + (s - 4)) * 4 + f] = sum;
      }
    }
    publish(f0 + s);
  }
  if (dblk) {                              // epilogue dense d = T-4..T-1
    for (int e = 0; e < 4; ++e) {
      int d = T_ - 4 + e;
      const _Float16* h1e = h1g + (d & 3) * SLOTH;
      f32x4 rd2;
      const _Float16* sD2 = h1e + (drb + dr) * PSL + dc * 8;   // FIX: +drb
      if (vD0) cload4(rd2, sD2);
      vwait0();
      const unsigned expD = (unsigned short)(d + 1);
      for (;;) {
        bool ok = !vD0 || (tagof(rd2) == expD);
        if (__all(ok)) break;
        if (vD0) cload4(rd2, sD2);
        vwait0();
      }
      __syncthreads();
      float* s_pd = (float*)s_h;
      if (vD0) {
        V4 hv; hv.f = rd2;
        float p0=0,p1=0,p2=0,p3=0;
        #pragma unroll
        for (int q = 0; q < 4; ++q) {
          h2 hp = hv.h[q];
          p0 = dot2f(hp, *(const h2*)(s_wd + 0*472 + dc*8 + 2*q), p0);
          p1 = dot2f(hp, *(const h2*)(s_wd + 1*472 + dc*8 + 2*q), p1);
          p2 = dot2f(hp, *(const h2*)(s_wd + 2*472 + dc*8 + 2*q), p2);
          p3 = dot2f(hp, *(const h2*)(s_wd + 3*472 + dc*8 + 2*q), p3);
        }
        f32x4 pv = {p0, p1, p2, p3};
        *(f32x4*)(s_pd + tid * 4) = pv;
      }
      __syncthreads();
      if (tid < 32) {
        int r8 = tid >> 2, f = tid & 3;
        float sum = bdv;
        for (int c = 0; c < 58; ++c) sum += s_pd[(r8 * 58 + c) * 4 + f];
        out[((grp * RG + drb + r8) * T_ + d) * 4 + f] = sum;
      }
      __syncthreads();
    }
  }
}

// ------- Layer 1: K = 464 packed h0(s) | 464 packed h1(s-1) -------
__device__ void run_l1(int jj, int grp,
    const float* __restrict__ Wx1, const float* __restrict__ Wh1, const float* __restrict__ b1,
    const _Float16* __restrict__ h0g, _Float16* __restrict__ h1g,
    int* f0, int* f1, unsigned char* smem)
{
  const int tid = threadIdx.x;
  _Float16* s_w = (_Float16*)smem;            // [84][928]
  _Float16* s_h = (_Float16*)(smem + SW1B);   // [16][232]
  const int c0 = (jj < 19) ? 3 * jj : 57;
  const int cn = (jj < 19) ? 3 : 1;
  const int u0 = c0 * 7;
  const int hi = (c0 + cn) * 7;
  const int nu = (hi > 400 ? 400 : hi) - u0;  // 21 or 1

  for (int idx = tid; idx < 84 * 928; idx += NTHR) {
    int col = idx / 928, k = idx - col * 928;
    int u = col >> 2, g = col & 3, uu = u0 + u;
    float v = 0.f;
    if (u < nu) {
      int q = (k < 464) ? k : (k - 464);
      int c = q >> 3, j = q & 7;
      if (j < 7) { int su = c * 7 + j;
        if (su < 400) v = (k < 464) ? Wx1[su * G4H + g * H_ + uu]
                                    : Wh1[su * G4H + g * H_ + uu]; }
    }
    s_w[idx] = (_Float16)v;
  }
  __syncthreads();

  const int cs = tid >> 4, ks = tid & 15;
  const int uu = u0 + cs;
  const bool act = cs < nu;
  float bi0 = 0, bi1 = 0, bi2 = 0, bi3 = 0;
  if (act) { bi0 = b1[uu]; bi1 = b1[H_ + uu]; bi2 = b1[2 * H_ + uu]; bi3 = b1[3 * H_ + uu]; }
  float cst = 0.f;

  const int i1 = tid + 512;
  const int r0 = tid / 58, cA = tid - 58 * r0;
  const bool v1 = i1 < 928;
  const int r1 = v1 ? i1 / 58 : 0, cB = v1 ? (i1 - 58 * (i1 / 58)) : 0;

  for (int s = 0; s < T_; ++s) {
    const _Float16* h0c = h0g + (s & 3) * SLOTH;
    const _Float16* h1p = h1g + ((s - 1) & 3) * SLOTH;
    _Float16*       h1n = h1g + (s & 3) * SLOTH;

    f32x4 rA0, rA1, rB0, rB1;
    const _Float16* sA0 = h0c + r0 * PSL + cA * 8;
    const _Float16* sA1 = h0c + r1 * PSL + cB * 8;
    const _Float16* sB0 = h1p + r0 * PSL + cA * 8;
    const _Float16* sB1 = h1p + r1 * PSL + cB * 8;
    cload4(rA0, sA0); if (v1) cload4(rA1, sA1);
    cload4(rB0, sB0); if (v1) cload4(rB1, sB1);

    if (tid == 0)            waitflag(f0 + s, N0);       // L0 (incl. dense of s-4) done
    if (tid == 64 && s >= 3) waitflag(f1 + s - 3, N1);   // FIX: siblings past phase B of s-3
    __syncthreads();

    const unsigned expA = (unsigned short)(s + 1);   // h0(s)
    const unsigned expB = (unsigned short)s;         // h1(s-1)
    vwait0();
    for (;;) {
      bool ok = (tagof(rA0) == expA) && (!v1 || tagof(rA1) == expA);
      if (__all(ok)) break;
      cload4(rA0, sA0); if (v1) cload4(rA1, sA1);
      vwait0();
    }

    float acc[16][4];
    #pragma unroll
    for (int r = 0; r < 16; ++r) { acc[r][0]=0; acc[r][1]=0; acc[r][2]=0; acc[r][3]=0; }

    if (cA < 29) *(f32x4*)(s_h + r0 * 232 + cA * 8) = rA0;
    if (v1 && cB < 29) *(f32x4*)(s_h + r1 * 232 + cB * 8) = rA1;
    __syncthreads();
    if (act) gchunkT<16>(acc, s_w, 928, s_h, 0, 29, ks, cs);
    __syncthreads();
    if (cA >= 29) *(f32x4*)(s_h + r0 * 232 + (cA - 29) * 8) = rA0;
    if (v1 && cB >= 29) *(f32x4*)(s_h + r1 * 232 + (cB - 29) * 8) = rA1;
    __syncthreads();
    if (act) gchunkT<16>(acc, s_w, 928, s_h, 232, 29, ks, cs);
    __syncthreads();

    // phase B: data loaded speculatively at step top — tag check usually free
    for (;;) {
      bool ok = (tagof(rB0) == expB) && (!v1 || tagof(rB1) == expB);
      if (__all(ok)) break;
      cload4(rB0, sB0); if (v1) cload4(rB1, sB1);
      vwait0();
    }
    if (cA < 29) *(f32x4*)(s_h + r0 * 232 + cA * 8) = rB0;
    if (v1 && cB < 29) *(f32x4*)(s_h + r1 * 232 + cB * 8) = rB1;
    __syncthreads();
    if (act) gchunkT<16>(acc, s_w, 928, s_h, 464, 29, ks, cs);
    __syncthreads();
    if (cA >= 29) *(f32x4*)(s_h + r0 * 232 + (cA - 29) * 8) = rB0;
    if (v1 && cB >= 29) *(f32x4*)(s_h + r1 * 232 + (cB - 29) * 8) = rB1;
    __syncthreads();
    if (act) gchunkT<16>(acc, s_w, 928, s_h, 696, 29, ks, cs);

    #pragma unroll
    for (int r = 0; r < 16; ++r)
      #pragma unroll
      for (int g = 0; g < 4; ++g) {
        float v = acc[r][g];
        v += __shfl_xor(v, 1); v += __shfl_xor(v, 2);
        v += __shfl_xor(v, 4); v += __shfl_xor(v, 8);
        acc[r][g] = v;
      }
    float g0 = 0, g1 = 0, g2 = 0, g3 = 0;
    #pragma unroll
    for (int r = 0; r < 16; ++r)
      if (ks == r) { g0 = acc[r][0]; g1 = acc[r][1]; g2 = acc[r][2]; g3 = acc[r][3]; }
    float hv = 0.f;
    if (act) {
      float iv = sigmf(g0+bi0), fv = sigmf(g1+bi1), gv = tanhf(g2+bi2), ov = sigmf(g3+bi3);
      cst = fv * cst + iv * gv;
      hv = ov * tanhf(cst);
    }
    __syncthreads();                       // reuse s_h as exchange
    if (cs < 24) s_h[ks * 24 + cs] = act ? (_Float16)hv : (_Float16)0.f;
    __syncthreads();
    if (tid < cn * 16) {
      int row = tid & 15, ci = tid >> 4;
      PK pk;
      #pragma unroll
      for (int j = 0; j < 7; ++j) {
        int su = (c0 + ci) * 7 + j;
        _Float16 hh = (su < u0 + nu) ? s_h[row * 24 + (su - u0)] : (_Float16)0.f;
        union { _Float16 h; unsigned short u; } cv; cv.h = hh;
        pk.u16[j] = cv.u;
      }
      pk.u16[7] = (unsigned short)(s + 1);
      cstore16(h1n + row * PSL + (c0 + ci) * 8, pk.f);
    }
    publish(f1 + s);
  }
}

__global__ __launch_bounds__(NTHR, 1) void rnn_kernel(
    const float* __restrict__ xr, const float* __restrict__ xc,
    const float* __restrict__ Wx0, const float* __restrict__ Wh0, const float* __restrict__ b0,
    const float* __restrict__ Wx1, const float* __restrict__ Wh1, const float* __restrict__ b1,
    const float* __restrict__ Wd, const float* __restrict__ bd,
    float* __restrict__ out, float* ws)
{
  __shared__ __align__(16) unsigned char smem[SMEMB];
  const int bid = blockIdx.x;
  const int grp = bid >> 5, j = bid & 31;
  int* f0 = (int*)ws + grp * 1024;
  int* f1 = (int*)ws + NG * 1024 + grp * 1024;
  _Float16* ring = (_Float16*)((char*)ws + FLAG_BYTES);
  _Float16* h0g = ring + grp * RINGH;
  _Float16* h1g = ring + NG * RINGH + grp * RINGH;
  if (j < N0)
    run_l0(j, grp, xr, xc, Wx0, Wh0, b0, Wd, bd, h0g, h1g, out, f0, f1, smem);
  else
    run_l1(j - N0, grp, Wx1, Wh1, b1, h0g, h1g, f0, f1, smem);
}

extern "C" void kernel_launch(void* const* d_in, const int* in_sizes, int n_in,
                              void* d_out, int out_size, void* d_ws, size_t ws_size,
                              hipStream_t stream) {
  const float* xr  = (const float*)d_in[0];
  const float* xc  = (const float*)d_in[1];
  const float* Wx0 = (const float*)d_in[2];
  const float* Wh0 = (const float*)d_in[3];
  const float* b0  = (const float*)d_in[4];
  const float* Wx1 = (const float*)d_in[5];
  const float* Wh1 = (const float*)d_in[6];
  const float* b1  = (const float*)d_in[7];
  const float* Wd  = (const float*)d_in[8];
  const float* bd  = (const float*)d_in[9];
  float* out = (float*)d_out;
  float* ws  = (float*)d_ws;

  // zero flags + both tagged rings each launch (tag 0 == valid step -1, zero data)
  hipMemsetAsync(d_ws, 0, WS_TOTAL, stream);
  hipLaunchKernelGGL(rnn_kernel, dim3(NBLK), dim3(NTHR), 0, stream,
                     xr, xc, Wx0, Wh0, b0, Wx1, Wh1, b1, Wd, bd, out, ws);
}

// Round 14
// 14700.482 us; speedup vs baseline: 1.0996x; 1.0996x over previous
//
#include <hip/hip_runtime.h>

#define T_ 1024
#define H_ 400
#define G4H 1600
#define NG 8            // batch groups (16 rows each)
#define RG 16           // rows per group
#define NBLK 256
#define NTHR 512
#define N0 14           // L0 blocks per group
#define N1 17           // L1 blocks per group
#define SLOT (RG * H_)  // 6400 halfs per h slot per group
#define SCOPE __HIP_MEMORY_SCOPE_AGENT

typedef float f32x4 __attribute__((ext_vector_type(4)));
typedef _Float16 h2 __attribute__((ext_vector_type(2)));
typedef _Float16 h4 __attribute__((ext_vector_type(4)));
union V4 { f32x4 f; h2 h[4]; };

// ---- workspace: per-group byte-flag arrays + h rings ----
// per group: f0[1024][16] | f1[1024][32] | fD[1024][4]  = 53248 bytes
#define FLG_G 53248
#define F1B 16384
#define FDB 49152
#define RING_OFF (NG * FLG_G)             // 425984
#define WS_TOTAL (RING_OFF + 2 * NG * 4 * SLOT * 2)   // + 819200 -> 1,245,184

// LDS: weight slice (col-major [cols][K+pad]) + stage [16][256] halfs
#define WS0 472                     // L0 K-stride (464 used)
#define WS1 808                     // L1 K-stride (800 used)
#define STGB 155136                 // stage offset = L1 weight bytes (96*808*2)
#define SMEMB (STGB + RG*256*2)     // 163328 <= 163840

__device__ __forceinline__ float sigmf(float x) { return 1.0f / (1.0f + __expf(-x)); }

// coherent 16B load (LLC-served, bypasses non-coherent L1/L2). Valid after vwait0().
__device__ __forceinline__ void cload4(f32x4& r, const void* p) {
  asm volatile("global_load_dwordx4 %0, %1, off sc0 sc1" : "=v"(r) : "v"(p) : "memory");
}
// plain cached 16B load (immutable inputs only)
__device__ __forceinline__ void pload4(f32x4& r, const void* p) {
  asm volatile("global_load_dwordx4 %0, %1, off" : "=v"(r) : "v"(p) : "memory");
}
// drain ALL outstanding vmem (count-independent -> spill-immune)
__device__ __forceinline__ void vwait0() {
  asm volatile("s_waitcnt vmcnt(0)" ::: "memory");
  __builtin_amdgcn_sched_barrier(0);   // rule #18
}

__device__ __forceinline__ float dot2f(h2 a, h2 b, float c) {
#if __has_builtin(__builtin_amdgcn_fdot2)
  return __builtin_amdgcn_fdot2(a, b, c, false);
#else
  return fmaf((float)a[0], (float)b[0], fmaf((float)a[1], (float)b[1], c));
#endif
}

// whole-wave poll: lanes 0..n-1 each watch one per-block byte flag (one cache line)
__device__ __forceinline__ void pollB(const unsigned char* p, int n) {
  const int lane = threadIdx.x & 63;
  for (;;) {
    int v = 1;
    if (lane < n)
      asm volatile("global_load_ubyte %0, %1, off sc0 sc1\n\ts_waitcnt vmcnt(0)"
                   : "=v"(v) : "v"(p + lane) : "memory");
    if (__all(v != 0)) return;
    __builtin_amdgcn_s_sleep(1);
  }
}
__device__ __forceinline__ void storeB1(unsigned char* p) {
  unsigned one = 1;
  asm volatile("global_store_byte %0, %1, off sc0 sc1" :: "v"(p), "v"(one) : "memory");
}
// publish: drain this block's h-stores, then set my own byte (no RMW serialization)
__device__ __forceinline__ void publishB(unsigned char* w) {
  asm volatile("s_waitcnt vmcnt(0)" ::: "memory");
  __syncthreads();
  if (threadIdx.x == 0) storeB1(w);
}
__device__ __forceinline__ void cstoreh(_Float16* p, float v) {
  union { _Float16 h; unsigned short s; } cv; cv.h = (_Float16)v;
  unsigned u = cv.s;
  asm volatile("global_store_short %0, %1, off sc0 sc1" :: "v"(p), "v"(u) : "memory");
}

// one K-chunk: acc[16 rows][4 gates] += h[r][i*8..] . w[unit cs][gate][k0w + i*8..]
__device__ __forceinline__ void gchunk(float (&acc)[16][4], const _Float16* s_w, int ws,
                                       const _Float16* s_h, int k0w, int nslot, int ks, int cs)
{
  for (int i = ks; i < nslot; i += 16) {
    V4 w0, w1, w2, w3;
    const _Float16* wb = s_w + (cs * 4) * ws + k0w + i * 8;
    w0.f = *(const f32x4*)(wb);
    w1.f = *(const f32x4*)(wb + ws);
    w2.f = *(const f32x4*)(wb + 2 * ws);
    w3.f = *(const f32x4*)(wb + 3 * ws);
    #pragma unroll
    for (int r = 0; r < 16; ++r) {
      V4 hv; hv.f = *(const f32x4*)(s_h + r * 256 + i * 8);
      #pragma unroll
      for (int q = 0; q < 4; ++q) {
        acc[r][0] = dot2f(hv.h[q], w0.h[q], acc[r][0]);
        acc[r][1] = dot2f(hv.h[q], w1.h[q], acc[r][1]);
        acc[r][2] = dot2f(hv.h[q], w2.h[q], acc[r][2]);
        acc[r][3] = dot2f(hv.h[q], w3.h[q], acc[r][3]);
      }
    }
  }
}

// ---------------- Layer 0: 16 rows, ~29 units. K = 464: h0(400)|x(56)|pad(8) ----------------
__device__ void run_l0(int jj, int grp,
    const float* __restrict__ xr, const float* __restrict__ xc,
    const float* __restrict__ Wx0, const float* __restrict__ Wh0, const float* __restrict__ b0,
    _Float16* __restrict__ h0g, unsigned char* f0, unsigned char* f1, unsigned char* smem)
{
  const int tid = threadIdx.x;
  _Float16* s_w = (_Float16*)smem;
  _Float16* s_h = (_Float16*)(smem + STGB);
  const int u0 = jj * H_ / N0, u1 = (jj + 1) * H_ / N0;

  for (int idx = tid; idx < 128 * WS0; idx += NTHR) {
    int col = idx / WS0, k = idx - col * WS0;
    int u = col >> 2, g = col & 3, uu = u0 + u;
    float v = 0.f;
    if (uu < u1 && k < 456)
      v = (k < 400) ? Wh0[k * G4H + g * H_ + uu] : Wx0[(k - 400) * G4H + g * H_ + uu];
    s_w[idx] = (_Float16)v;
  }
  __syncthreads();

  const int cs = tid >> 4, ks = tid & 15;
  const int uu = u0 + cs;
  const bool act = (uu < u1);
  float bi0 = 0.f, bi1 = 0.f, bi2 = 0.f, bi3 = 0.f;
  if (act) { bi0 = b0[uu]; bi1 = b0[H_ + uu]; bi2 = b0[2 * H_ + uu]; bi3 = b0[3 * H_ + uu]; }
  float cst = 0.f;   // cell state of (row ks, unit uu)

  f32x4 rx, rA, rB;
  for (int s = 0; s < T_; ++s) {
    const _Float16* h0p = h0g + ((s - 1) & 3) * SLOT;
    _Float16*       h0n = h0g + (s & 3) * SLOT;

    // x pre-issue (plain cached): 16 rows x 14 x4-slots = 224 loads
    if (tid < 224) {
      int row = tid / 14, c4 = tid - row * 14, kf = c4 * 4;
      int rg = grp * RG + row;
      const float* p = (kf < 40) ? xr + (rg * T_ + s) * 40 + kf
                                 : xc + (rg * T_ + s) * 16 + (kf - 40);
      pload4(rx, p);
    }
    if (tid < 64 && s >= 1)               pollB(f0 + (s - 1) * 16, N0);  // h0(s-1) complete
    if (tid >= 64 && tid < 128 && s >= 4) pollB(f1 + (s - 4) * 32, N1);  // slot s&3 free
    __syncthreads();

    // chunk 0: K[0,256): 1 cload/thread; prefetch chunk-1 h after its wait
    { int row = tid >> 5, sl = tid & 31;
      cload4(rA, h0p + row * H_ + sl * 8); }
    vwait0();                                   // drains rx + c0
    { int row = tid >> 5, sl = tid & 31;
      *(f32x4*)(s_h + row * 256 + sl * 8) = rA; }
    if (tid < 288) {                            // c1 h-part: K[256,400): 18 slots/row
      int row = tid / 18, sl = tid - row * 18;
      cload4(rB, h0p + row * H_ + 256 + sl * 8);
    }
    __syncthreads();

    float acc[16][4];
    #pragma unroll
    for (int r = 0; r < 16; ++r)
      #pragma unroll
      for (int g = 0; g < 4; ++g) acc[r][g] = 0.f;

    gchunk(acc, s_w, WS0, s_h, 0, 32, ks, cs);
    __syncthreads();
    vwait0();
    if (tid < 288) { int row = tid / 18, sl = tid - row * 18;
      *(f32x4*)(s_h + row * 256 + sl * 8) = rB; }
    if (tid < 224) { int row = tid / 14, c4 = tid - row * 14;
      h4 hv; hv[0] = (_Float16)rx[0]; hv[1] = (_Float16)rx[1];
             hv[2] = (_Float16)rx[2]; hv[3] = (_Float16)rx[3];
      *(h4*)(s_h + row * 256 + 144 + c4 * 4) = hv; }   // x -> cols 144-199
    __syncthreads();
    // cols 200-207 keep chunk-0 h values (finite; zero weights at K 456-463)
    gchunk(acc, s_w, WS0, s_h, 256, 26, ks, cs);

    #pragma unroll
    for (int r = 0; r < 16; ++r)
      #pragma unroll
      for (int g = 0; g < 4; ++g) {
        float v = acc[r][g];
        v += __shfl_xor(v, 1); v += __shfl_xor(v, 2);
        v += __shfl_xor(v, 4); v += __shfl_xor(v, 8);
        acc[r][g] = v;
      }
    float g0 = 0.f, g1 = 0.f, g2 = 0.f, g3 = 0.f;
    #pragma unroll
    for (int r = 0; r < 16; ++r)
      if (ks == r) { g0 = acc[r][0]; g1 = acc[r][1]; g2 = acc[r][2]; g3 = acc[r][3]; }
    float iv = sigmf(g0 + bi0), fv = sigmf(g1 + bi1);
    float gv = tanhf(g2 + bi2), ov = sigmf(g3 + bi3);
    cst = fv * cst + iv * gv;
    float hval = ov * tanhf(cst);
    if (act) cstoreh(h0n + ks * H_ + uu, hval);
    publishB(f0 + s * 16 + jj);
  }
}

// ---------------- Layer 1: 16 rows, ~24 units. K = 800 split: h0-half first, h1-half late ----------------
__device__ void run_l1(int jj, int grp,
    const float* __restrict__ Wx1, const float* __restrict__ Wh1, const float* __restrict__ b1,
    const _Float16* __restrict__ h0g, _Float16* __restrict__ h1g,
    unsigned char* f0, unsigned char* f1, unsigned char* fD, unsigned char* smem)
{
  const int tid = threadIdx.x;
  _Float16* s_w = (_Float16*)smem;
  _Float16* s_h = (_Float16*)(smem + STGB);
  const int u0 = jj * H_ / N1, u1 = (jj + 1) * H_ / N1;

  for (int idx = tid; idx < 96 * WS1; idx += NTHR) {
    int col = idx / WS1, k = idx - col * WS1;
    int u = col >> 2, g = col & 3, uu = u0 + u;
    float v = 0.f;
    if (uu < u1 && k < 800)
      v = (k < 400) ? Wx1[k * G4H + g * H_ + uu] : Wh1[(k - 400) * G4H + g * H_ + uu];
    s_w[idx] = (_Float16)v;
  }
  __syncthreads();

  const bool thr = tid < 384;                 // 24 cs-groups x 16 ks
  const int cs = tid >> 4, ks = tid & 15;
  const int uu = u0 + cs;
  const bool act = thr && (uu < u1);
  float bi0 = 0.f, bi1 = 0.f, bi2 = 0.f, bi3 = 0.f;
  if (act) { bi0 = b1[uu]; bi1 = b1[H_ + uu]; bi2 = b1[2 * H_ + uu]; bi3 = b1[3 * H_ + uu]; }
  float cst = 0.f;

  f32x4 rA, rB;
  for (int s = 0; s < T_; ++s) {
    const _Float16* h0c = h0g + (s & 3) * SLOT;          // h0(s)
    const _Float16* h1p = h1g + ((s - 1) & 3) * SLOT;    // h1(s-1)
    _Float16*       h1n = h1g + (s & 3) * SLOT;

    // ---- phase A: h0(s) half (pre-published thanks to L0's lead) ----
    if (tid < 64)                         pollB(f0 + s * 16, N0);        // h0(s) ready
    if (tid >= 64 && tid < 128 && s >= 4) pollB(fD + (s - 4) * 4, 1);    // dense freed slot
    __syncthreads();

    float acc[16][4];
    #pragma unroll
    for (int r = 0; r < 16; ++r)
      #pragma unroll
      for (int g = 0; g < 4; ++g) acc[r][g] = 0.f;

    { int row = tid >> 5, sl = tid & 31;                 // h0[0,256)
      cload4(rA, h0c + row * H_ + sl * 8); }
    if (tid < 288) { int row = tid / 18, sl = tid - row * 18;   // h0[256,400)
      cload4(rB, h0c + row * H_ + 256 + sl * 8); }
    vwait0();
    { int row = tid >> 5, sl = tid & 31;
      *(f32x4*)(s_h + row * 256 + sl * 8) = rA; }
    __syncthreads();
    if (thr) gchunk(acc, s_w, WS1, s_h, 0, 32, ks, cs);
    __syncthreads();
    if (tid < 288) { int row = tid / 18, sl = tid - row * 18;
      *(f32x4*)(s_h + row * 256 + sl * 8) = rB; }
    __syncthreads();
    if (thr) gchunk(acc, s_w, WS1, s_h, 256, 18, ks, cs);

    // ---- phase B: h1(s-1) half (poll AFTER phase A hid the jitter) ----
    if (tid < 64 && s >= 1) pollB(f1 + (s - 1) * 32, N1);    // h1(s-1) ready
    __syncthreads();
    { int row = tid >> 5, sl = tid & 31;                 // h1[0,256) -> K 400..656
      cload4(rA, h1p + row * H_ + sl * 8); }
    if (tid < 288) { int row = tid / 18, sl = tid - row * 18;   // h1[256,400) -> K 656..800
      cload4(rB, h1p + row * H_ + 256 + sl * 8); }
    vwait0();
    { int row = tid >> 5, sl = tid & 31;
      *(f32x4*)(s_h + row * 256 + sl * 8) = rA; }
    __syncthreads();
    if (thr) gchunk(acc, s_w, WS1, s_h, 400, 32, ks, cs);
    __syncthreads();
    if (tid < 288) { int row = tid / 18, sl = tid - row * 18;
      *(f32x4*)(s_h + row * 256 + sl * 8) = rB; }
    __syncthreads();
    if (thr) gchunk(acc, s_w, WS1, s_h, 656, 18, ks, cs);

    if (thr) {
      #pragma unroll
      for (int r = 0; r < 16; ++r)
        #pragma unroll
        for (int g = 0; g < 4; ++g) {
          float v = acc[r][g];
          v += __shfl_xor(v, 1); v += __shfl_xor(v, 2);
          v += __shfl_xor(v, 4); v += __shfl_xor(v, 8);
          acc[r][g] = v;
        }
      float g0 = 0.f, g1 = 0.f, g2 = 0.f, g3 = 0.f;
      #pragma unroll
      for (int r = 0; r < 16; ++r)
        if (ks == r) { g0 = acc[r][0]; g1 = acc[r][1]; g2 = acc[r][2]; g3 = acc[r][3]; }
      float iv = sigmf(g0 + bi0), fv = sigmf(g1 + bi1);
      float gv = tanhf(g2 + bi2), ov = sigmf(g3 + bi3);
      cst = fv * cst + iv * gv;
      float hval = ov * tanhf(cst);
      if (act) cstoreh(h1n + ks * H_ + uu, hval);
    }
    publishB(f1 + s * 32 + jj);
  }
}

// ---------------- Dense: out(s) = h1(s) @ Wd + bd, 16 rows ----------------
__device__ void run_dense(int grp, const float* __restrict__ Wd, const float* __restrict__ bd,
                          const _Float16* __restrict__ h1g, float* __restrict__ out,
                          unsigned char* f1, unsigned char* fD, unsigned char* smem)
{
  const int tid = threadIdx.x;
  _Float16* s_wd = (_Float16*)smem;   // [4][404]
  for (int idx = tid; idx < 1600; idx += NTHR) {
    int k = idx >> 2, f = idx & 3;
    s_wd[f * 404 + k] = (_Float16)Wd[idx];
  }
  __syncthreads();
  const bool thr = tid < 256;
  const int row = tid >> 4, ks = tid & 15;
  const int rg = grp * RG + row;
  const float bdv = (ks < 4) ? bd[ks] : 0.f;
  f32x4 r0, r1, r2, r3;
  for (int s = 0; s < T_; ++s) {
    if (tid < 64) pollB(f1 + s * 32, N1);
    __syncthreads();
    const _Float16* hrow = h1g + (s & 3) * SLOT + row * H_;
    if (thr) {
      cload4(r0, hrow + ks * 8);
      cload4(r1, hrow + (ks + 16) * 8);
      cload4(r2, hrow + (ks + 32) * 8);
      if (ks < 2) cload4(r3, hrow + (48 + ks) * 8);
    }
    vwait0();
    __syncthreads();                       // all reads of slot s&3 retired
    if (tid == 0) storeB1(fD + s * 4);     // release slot (no RMW)
    if (thr) {
      float a0 = 0.f, a1 = 0.f, a2 = 0.f, a3 = 0.f;
      auto dproc = [&](const f32x4& rv, int sl) {
        V4 hv; hv.f = rv;
        #pragma unroll
        for (int q = 0; q < 4; ++q) {
          int k = sl * 8 + q * 2;
          h2 hp = hv.h[q];
          a0 = dot2f(hp, *(const h2*)(s_wd + k), a0);
          a1 = dot2f(hp, *(const h2*)(s_wd + 404 + k), a1);
          a2 = dot2f(hp, *(const h2*)(s_wd + 808 + k), a2);
          a3 = dot2f(hp, *(const h2*)(s_wd + 1212 + k), a3);
        }
      };
      dproc(r0, ks); dproc(r1, ks + 16); dproc(r2, ks + 32);
      if (ks < 2) dproc(r3, 48 + ks);
      a0 += __shfl_xor(a0, 1); a0 += __shfl_xor(a0, 2); a0 += __shfl_xor(a0, 4); a0 += __shfl_xor(a0, 8);
      a1 += __shfl_xor(a1, 1); a1 += __shfl_xor(a1, 2); a1 += __shfl_xor(a1, 4); a1 += __shfl_xor(a1, 8);
      a2 += __shfl_xor(a2, 1); a2 += __shfl_xor(a2, 2); a2 += __shfl_xor(a2, 4); a2 += __shfl_xor(a2, 8);
      a3 += __shfl_xor(a3, 1); a3 += __shfl_xor(a3, 2); a3 += __shfl_xor(a3, 4); a3 += __shfl_xor(a3, 8);
      float o = a0;
      if (ks == 1) o = a1;
      if (ks == 2) o = a2;
      if (ks == 3) o = a3;
      if (ks < 4) out[(rg * T_ + s) * 4 + ks] = o + bdv;
    }
  }
}

__global__ __launch_bounds__(NTHR, 1) void rnn_kernel(
    const float* __restrict__ xr, const float* __restrict__ xc,
    const float* __restrict__ Wx0, const float* __restrict__ Wh0, const float* __restrict__ b0,
    const float* __restrict__ Wx1, const float* __restrict__ Wh1, const float* __restrict__ b1,
    const float* __restrict__ Wd, const float* __restrict__ bd,
    float* __restrict__ out, float* ws)
{
  __shared__ __align__(16) unsigned char smem[SMEMB];
  const int bid = blockIdx.x;
  const int grp = bid >> 5, j = bid & 31;
  unsigned char* fg = (unsigned char*)ws + grp * FLG_G;
  unsigned char* f0 = fg;
  unsigned char* f1 = fg + F1B;
  unsigned char* fD = fg + FDB;
  _Float16* h0buf = (_Float16*)((char*)ws + RING_OFF);    // [NG][4][SLOT]
  _Float16* h1buf = h0buf + NG * 4 * SLOT;
  _Float16* h0g = h0buf + grp * 4 * SLOT;
  _Float16* h1g = h1buf + grp * 4 * SLOT;
  if (j < N0)            run_l0(j, grp, xr, xc, Wx0, Wh0, b0, h0g, f0, f1, smem);
  else if (j < N0 + N1)  run_l1(j - N0, grp, Wx1, Wh1, b1, h0g, h1g, f0, f1, fD, smem);
  else                   run_dense(grp, Wd, bd, h1g, out, f1, fD, smem);
}

extern "C" void kernel_launch(void* const* d_in, const int* in_sizes, int n_in,
                              void* d_out, int out_size, void* d_ws, size_t ws_size,
                              hipStream_t stream) {
  const float* xr  = (const float*)d_in[0];
  const float* xc  = (const float*)d_in[1];
  const float* Wx0 = (const float*)d_in[2];
  const float* Wh0 = (const float*)d_in[3];
  const float* b0  = (const float*)d_in[4];
  const float* Wx1 = (const float*)d_in[5];
  const float* Wh1 = (const float*)d_in[6];
  const float* b1  = (const float*)d_in[7];
  const float* Wd  = (const float*)d_in[8];
  const float* bd  = (const float*)d_in[9];
  float* out = (float*)d_out;
  float* ws  = (float*)d_ws;

  // zero byte flags + both h rings (re-zeroed every launch -> deterministic replays)
  hipMemsetAsync(d_ws, 0, WS_TOTAL, stream);
  hipLaunchKernelGGL(rnn_kernel, dim3(NBLK), dim3(NTHR), 0, stream,
                     xr, xc, Wx0, Wh0, b0, Wx1, Wh1, b1, Wd, bd, out, ws);
}

// Round 15
// 4055.689 us; speedup vs baseline: 3.9855x; 3.6247x over previous
//
#include <hip/hip_runtime.h>

#define T_ 1024
#define H_ 400
#define G4H 1600
#define NG 8            // batch groups (16 rows each)
#define RG 16           // rows per group
#define NBLK 256
#define NTHR 512
#define N0 14           // L0 blocks per group
#define N1 17           // L1 blocks per group
#define SLOT (RG * H_)  // 6400 halfs per h slot per group
#define SCOPE __HIP_MEMORY_SCOPE_AGENT

typedef float f32x4 __attribute__((ext_vector_type(4)));
typedef _Float16 f16x8 __attribute__((ext_vector_type(8)));
typedef _Float16 h2 __attribute__((ext_vector_type(2)));
typedef _Float16 h4 __attribute__((ext_vector_type(4)));
union V4 { f32x4 f; h2 h[4]; };

// ---- workspace: per-group byte-flag arrays + h rings (identical to r14) ----
#define FLG_G 53248
#define F1B 16384
#define FDB 49152
#define RING_OFF (NG * FLG_G)             // 425984
#define WS_TOTAL (RING_OFF + 2 * NG * 4 * SLOT * 2)   // 1,245,184

// LDS: A-fragment staging + f32 gate exchange (weights now live in VGPRs)
// L0: s_a [15 kt][512 halfs] = 15360B, s_gs [16][128] f32 at 15360 (8192B)
// L1: s_a [25 kt][512 halfs] = 25600B, s_gs [16][96]  f32 at 25600 (6144B)
#define SGS0 15360
#define SGS1 25600
#define SMEMB 32768

__device__ __forceinline__ float sigmf(float x) { return 1.0f / (1.0f + __expf(-x)); }

__device__ __forceinline__ void cload4(f32x4& r, const void* p) {
  asm volatile("global_load_dwordx4 %0, %1, off sc0 sc1" : "=v"(r) : "v"(p) : "memory");
}
__device__ __forceinline__ void pload4(f32x4& r, const void* p) {   // immutable inputs
  asm volatile("global_load_dwordx4 %0, %1, off" : "=v"(r) : "v"(p) : "memory");
}
__device__ __forceinline__ void vwait0() {
  asm volatile("s_waitcnt vmcnt(0)" ::: "memory");
  __builtin_amdgcn_sched_barrier(0);   // rule #18
}

__device__ __forceinline__ float dot2f(h2 a, h2 b, float c) {
#if __has_builtin(__builtin_amdgcn_fdot2)
  return __builtin_amdgcn_fdot2(a, b, c, false);
#else
  return fmaf((float)a[0], (float)b[0], fmaf((float)a[1], (float)b[1], c));
#endif
}

// whole-wave poll: lanes 0..n-1 each watch one per-block byte flag (one cache line)
__device__ __forceinline__ void pollB(const unsigned char* p, int n) {
  const int lane = threadIdx.x & 63;
  for (;;) {
    int v = 1;
    if (lane < n)
      asm volatile("global_load_ubyte %0, %1, off sc0 sc1\n\ts_waitcnt vmcnt(0)"
                   : "=v"(v) : "v"(p + lane) : "memory");
    if (__all(v != 0)) return;
    __builtin_amdgcn_s_sleep(1);
  }
}
__device__ __forceinline__ void storeB1(unsigned char* p) {
  unsigned one = 1;
  asm volatile("global_store_byte %0, %1, off sc0 sc1" :: "v"(p), "v"(one) : "memory");
}
__device__ __forceinline__ void publishB(unsigned char* w) {
  asm volatile("s_waitcnt vmcnt(0)" ::: "memory");
  __syncthreads();
  if (threadIdx.x == 0) storeB1(w);
}
__device__ __forceinline__ void cstoreh(_Float16* p, float v) {
  union { _Float16 h; unsigned short s; } cv; cv.h = (_Float16)v;
  unsigned u = cv.s;
  asm volatile("global_store_short %0, %1, off sc0 sc1" :: "v"(p), "v"(u) : "memory");
}

// A-fragment staging offset (halfs): kt-tile, k-sub-block (0..3), batch row
__device__ __forceinline__ int astg(int kslot, int row) {
  // kslot = global_k >> 3; kt = kslot>>2; sub = kslot&3
  return (kslot >> 2) * 512 + (kslot & 3) * 128 + row * 8;
}

// ---------------- Layer 0: 16 rows, ~29 units (8 col-tiles). K = 480: h0(400)|x(56)|pad ----------------
__device__ void run_l0(int jj, int grp,
    const float* __restrict__ xr, const float* __restrict__ xc,
    const float* __restrict__ Wx0, const float* __restrict__ Wh0, const float* __restrict__ b0,
    _Float16* __restrict__ h0g, unsigned char* f0, unsigned char* f1, unsigned char* smem)
{
  const int tid = threadIdx.x;
  _Float16* s_a = (_Float16*)smem;             // [15][512] halfs
  float*    s_gs = (float*)(smem + SGS0);      // [16][128] f32
  const int u0 = jj * H_ / N0, u1 = (jj + 1) * H_ / N0;
  const int lane = tid & 63, wv = tid >> 6;

  for (int idx = tid; idx < 15 * 512; idx += NTHR) s_a[idx] = (_Float16)0.f;

  // B-fragments (weights) in registers: tile = wv, 15 K-tiles
  const int fc = lane & 15, kb = (lane >> 4) * 8;
  const int col = wv * 16 + fc, ul = col >> 2, g = col & 3, uuc = u0 + ul;
  const bool cact = (uuc < u1);
  f16x8 wreg[15];
  #pragma unroll
  for (int kt = 0; kt < 15; ++kt) {
    #pragma unroll
    for (int j = 0; j < 8; ++j) {
      int k = kt * 32 + kb + j;
      float v = 0.f;
      if (cact) {
        if (k < 400)      v = Wh0[k * G4H + g * H_ + uuc];
        else if (k < 456) v = Wx0[(k - 400) * G4H + g * H_ + uuc];
      }
      wreg[kt][j] = (_Float16)v;
    }
  }
  const float bval = cact ? b0[g * H_ + uuc] : 0.f;
  __syncthreads();

  // cell-update thread mapping: (row ks, unit u0+cs)
  const int cs = tid >> 4, ks = tid & 15;
  const int uu = u0 + cs;
  const bool act = (uu < u1);
  float cst = 0.f;

  f32x4 rx, rA, rB;
  for (int s = 0; s < T_; ++s) {
    const _Float16* h0p = h0g + ((s - 1) & 3) * SLOT;
    _Float16*       h0n = h0g + (s & 3) * SLOT;

    if (tid < 224) {          // x pre-issue (plain cached)
      int row = tid / 14, c4 = tid - row * 14, kf = c4 * 4;
      int rg = grp * RG + row;
      const float* p = (kf < 40) ? xr + (rg * T_ + s) * 40 + kf
                                 : xc + (rg * T_ + s) * 16 + (kf - 40);
      pload4(rx, p);
    }
    if (tid < 64 && s >= 1)               pollB(f0 + (s - 1) * 16, N0);
    if (tid >= 64 && tid < 128 && s >= 4) pollB(f1 + (s - 4) * 32, N1);
    __syncthreads();

    { int row = tid >> 5, sl = tid & 31;             // K[0,256) -> kt 0..7
      cload4(rA, h0p + row * H_ + sl * 8); }
    vwait0();                                        // drains rx + rA
    { int row = tid >> 5, sl = tid & 31;
      *(f32x4*)(s_a + astg(sl, row)) = rA; }
    if (tid < 288) {                                  // K[256,400) -> kslot 32..49
      int row = tid / 18, sl = tid - row * 18;
      cload4(rB, h0p + row * H_ + 256 + sl * 8);
    }
    __syncthreads();

    f32x4 acc = {bval, bval, bval, bval};
    #pragma unroll
    for (int kt = 0; kt < 8; ++kt) {
      f16x8 a = *(const f16x8*)(s_a + kt * 512 + lane * 8);
      acc = __builtin_amdgcn_mfma_f32_16x16x32_f16(a, wreg[kt], acc, 0, 0, 0);
    }
    __syncthreads();
    vwait0();
    if (tid < 288) { int row = tid / 18, sl = tid - row * 18;
      *(f32x4*)(s_a + astg(32 + sl, row)) = rB; }
    if (tid < 224) {                                  // x -> K 400..455
      int row = tid / 14, c4 = tid - row * 14;
      int gK = 400 + c4 * 4;
      h4 hv; hv[0] = (_Float16)rx[0]; hv[1] = (_Float16)rx[1];
             hv[2] = (_Float16)rx[2]; hv[3] = (_Float16)rx[3];
      *(h4*)(s_a + astg(gK >> 3, row) + (gK & 7)) = hv;
    }
    __syncthreads();
    #pragma unroll
    for (int kt = 8; kt < 15; ++kt) {
      f16x8 a = *(const f16x8*)(s_a + kt * 512 + lane * 8);
      acc = __builtin_amdgcn_mfma_f32_16x16x32_f16(a, wreg[kt], acc, 0, 0, 0);
    }

    // epilogue: D (col=lane&15, row=(lane>>4)*4+j) -> exchange -> cell
    { int q = lane >> 4;
      #pragma unroll
      for (int j = 0; j < 4; ++j)
        s_gs[(q * 4 + j) * 128 + wv * 16 + fc] = acc[j];
    }
    __syncthreads();
    if (act) {
      f32x4 gt = *(const f32x4*)(s_gs + ks * 128 + cs * 4);
      float iv = sigmf(gt[0]), fv = sigmf(gt[1]);
      float gv = tanhf(gt[2]), ov = sigmf(gt[3]);
      cst = fv * cst + iv * gv;
      cstoreh(h0n + ks * H_ + uu, ov * tanhf(cst));
    }
    publishB(f0 + s * 16 + jj);
  }
}

// ---------------- Layer 1: 16 rows, ~24 units (6 col-tiles). K = 800: h0(s)|h1(s-1) ----------------
__device__ void run_l1(int jj, int grp,
    const float* __restrict__ Wx1, const float* __restrict__ Wh1, const float* __restrict__ b1,
    const _Float16* __restrict__ h0g, _Float16* __restrict__ h1g,
    unsigned char* f0, unsigned char* f1, unsigned char* fD, unsigned char* smem)
{
  const int tid = threadIdx.x;
  _Float16* s_a = (_Float16*)smem;             // [25][512] halfs
  float*    s_gs = (float*)(smem + SGS1);      // [16][96] f32
  const int u0 = jj * H_ / N1, u1 = (jj + 1) * H_ / N1;
  const int lane = tid & 63, wv = tid >> 6;
  const bool mfw = wv < 6;

  for (int idx = tid; idx < 25 * 512; idx += NTHR) s_a[idx] = (_Float16)0.f;

  const int fc = lane & 15, kb = (lane >> 4) * 8;
  const int col = wv * 16 + fc, ul = col >> 2, g = col & 3, uuc = u0 + ul;
  const bool cact = mfw && (uuc < u1);
  f16x8 wreg[25];
  #pragma unroll
  for (int kt = 0; kt < 25; ++kt) {
    #pragma unroll
    for (int j = 0; j < 8; ++j) {
      int k = kt * 32 + kb + j;
      float v = 0.f;
      if (cact) v = (k < 400) ? Wx1[k * G4H + g * H_ + uuc]
                              : Wh1[(k - 400) * G4H + g * H_ + uuc];
      wreg[kt][j] = (_Float16)v;
    }
  }
  const float bval = cact ? b1[g * H_ + uuc] : 0.f;
  __syncthreads();

  const bool thr = tid < 384;
  const int cs = tid >> 4, ks = tid & 15;
  const int uu = u0 + cs;
  const bool act = thr && (uu < u1);
  float cst = 0.f;

  f32x4 rA, rB;
  for (int s = 0; s < T_; ++s) {
    const _Float16* h0c = h0g + (s & 3) * SLOT;          // h0(s)
    const _Float16* h1p = h1g + ((s - 1) & 3) * SLOT;    // h1(s-1)
    _Float16*       h1n = h1g + (s & 3) * SLOT;

    // ---- phase A: h0(s) half (K 0..399 -> kt 0..12 partial) ----
    if (tid < 64)                         pollB(f0 + s * 16, N0);
    if (tid >= 64 && tid < 128 && s >= 4) pollB(fD + (s - 4) * 4, 1);
    __syncthreads();

    { int row = tid >> 5, sl = tid & 31;               // h0 K[0,256): kslot 0..31
      cload4(rA, h0c + row * H_ + sl * 8); }
    if (tid < 288) { int row = tid / 18, sl = tid - row * 18;   // h0 K[256,400): kslot 32..49
      cload4(rB, h0c + row * H_ + 256 + sl * 8); }
    vwait0();
    { int row = tid >> 5, sl = tid & 31;
      *(f32x4*)(s_a + astg(sl, row)) = rA; }
    __syncthreads();

    f32x4 acc = {bval, bval, bval, bval};
    if (mfw) {
      #pragma unroll
      for (int kt = 0; kt < 8; ++kt) {
        f16x8 a = *(const f16x8*)(s_a + kt * 512 + lane * 8);
        acc = __builtin_amdgcn_mfma_f32_16x16x32_f16(a, wreg[kt], acc, 0, 0, 0);
      }
    }
    __syncthreads();
    if (tid < 288) { int row = tid / 18, sl = tid - row * 18;
      *(f32x4*)(s_a + astg(32 + sl, row)) = rB; }
    __syncthreads();
    if (mfw) {
      #pragma unroll
      for (int kt = 8; kt < 12; ++kt) {
        f16x8 a = *(const f16x8*)(s_a + kt * 512 + lane * 8);
        acc = __builtin_amdgcn_mfma_f32_16x16x32_f16(a, wreg[kt], acc, 0, 0, 0);
      }
    }

    // ---- phase B: h1(s-1) half (K 400..799 -> kslot 50..99) ----
    if (tid < 64 && s >= 1) pollB(f1 + (s - 1) * 32, N1);
    __syncthreads();
    { int row = tid >> 5, sl = tid & 31;               // h1 [0,256): kslot 50..81
      cload4(rA, h1p + row * H_ + sl * 8); }
    if (tid < 288) { int row = tid / 18, sl = tid - row * 18;   // h1 [256,400): kslot 82..99
      cload4(rB, h1p + row * H_ + 256 + sl * 8); }
    vwait0();
    { int row = tid >> 5, sl = tid & 31;
      *(f32x4*)(s_a + astg(50 + sl, row)) = rA; }
    __syncthreads();
    if (mfw) {
      #pragma unroll
      for (int kt = 12; kt < 20; ++kt) {
        f16x8 a = *(const f16x8*)(s_a + kt * 512 + lane * 8);
        acc = __builtin_amdgcn_mfma_f32_16x16x32_f16(a, wreg[kt], acc, 0, 0, 0);
      }
    }
    __syncthreads();
    if (tid < 288) { int row = tid / 18, sl = tid - row * 18;
      *(f32x4*)(s_a + astg(82 + sl, row)) = rB; }
    __syncthreads();
    if (mfw) {
      #pragma unroll
      for (int kt = 20; kt < 25; ++kt) {
        f16x8 a = *(const f16x8*)(s_a + kt * 512 + lane * 8);
        acc = __builtin_amdgcn_mfma_f32_16x16x32_f16(a, wreg[kt], acc, 0, 0, 0);
      }
    }

    // epilogue
    if (mfw) {
      int q = lane >> 4;
      #pragma unroll
      for (int j = 0; j < 4; ++j)
        s_gs[(q * 4 + j) * 96 + wv * 16 + fc] = acc[j];
    }
    __syncthreads();
    if (act) {
      f32x4 gt = *(const f32x4*)(s_gs + ks * 96 + cs * 4);
      float iv = sigmf(gt[0]), fv = sigmf(gt[1]);
      float gv = tanhf(gt[2]), ov = sigmf(gt[3]);
      cst = fv * cst + iv * gv;
      cstoreh(h1n + ks * H_ + uu, ov * tanhf(cst));
    }
    publishB(f1 + s * 32 + jj);
  }
}

// ---------------- Dense: out(s) = h1(s) @ Wd + bd, 16 rows (r14 verbatim) ----------------
__device__ void run_dense(int grp, const float* __restrict__ Wd, const float* __restrict__ bd,
                          const _Float16* __restrict__ h1g, float* __restrict__ out,
                          unsigned char* f1, unsigned char* fD, unsigned char* smem)
{
  const int tid = threadIdx.x;
  _Float16* s_wd = (_Float16*)smem;   // [4][404]
  for (int idx = tid; idx < 1600; idx += NTHR) {
    int k = idx >> 2, f = idx & 3;
    s_wd[f * 404 + k] = (_Float16)Wd[idx];
  }
  __syncthreads();
  const bool thr = tid < 256;
  const int row = tid >> 4, ks = tid & 15;
  const int rg = grp * RG + row;
  const float bdv = (ks < 4) ? bd[ks] : 0.f;
  f32x4 r0, r1, r2, r3;
  for (int s = 0; s < T_; ++s) {
    if (tid < 64) pollB(f1 + s * 32, N1);
    __syncthreads();
    const _Float16* hrow = h1g + (s & 3) * SLOT + row * H_;
    if (thr) {
      cload4(r0, hrow + ks * 8);
      cload4(r1, hrow + (ks + 16) * 8);
      cload4(r2, hrow + (ks + 32) * 8);
      if (ks < 2) cload4(r3, hrow + (48 + ks) * 8);
    }
    vwait0();
    __syncthreads();                       // all reads of slot s&3 retired
    if (tid == 0) storeB1(fD + s * 4);     // release slot
    if (thr) {
      float a0 = 0.f, a1 = 0.f, a2 = 0.f, a3 = 0.f;
      auto dproc = [&](const f32x4& rv, int sl) {
        V4 hv; hv.f = rv;
        #pragma unroll
        for (int q = 0; q < 4; ++q) {
          int k = sl * 8 + q * 2;
          h2 hp = hv.h[q];
          a0 = dot2f(hp, *(const h2*)(s_wd + k), a0);
          a1 = dot2f(hp, *(const h2*)(s_wd + 404 + k), a1);
          a2 = dot2f(hp, *(const h2*)(s_wd + 808 + k), a2);
          a3 = dot2f(hp, *(const h2*)(s_wd + 1212 + k), a3);
        }
      };
      dproc(r0, ks); dproc(r1, ks + 16); dproc(r2, ks + 32);
      if (ks < 2) dproc(r3, 48 + ks);
      a0 += __shfl_xor(a0, 1); a0 += __shfl_xor(a0, 2); a0 += __shfl_xor(a0, 4); a0 += __shfl_xor(a0, 8);
      a1 += __shfl_xor(a1, 1); a1 += __shfl_xor(a1, 2); a1 += __shfl_xor(a1, 4); a1 += __shfl_xor(a1, 8);
      a2 += __shfl_xor(a2, 1); a2 += __shfl_xor(a2, 2); a2 += __shfl_xor(a2, 4); a2 += __shfl_xor(a2, 8);
      a3 += __shfl_xor(a3, 1); a3 += __shfl_xor(a3, 2); a3 += __shfl_xor(a3, 4); a3 += __shfl_xor(a3, 8);
      float o = a0;
      if (ks == 1) o = a1;
      if (ks == 2) o = a2;
      if (ks == 3) o = a3;
      if (ks < 4) out[(rg * T_ + s) * 4 + ks] = o + bdv;
    }
  }
}

__global__ __launch_bounds__(NTHR, 1) void rnn_kernel(
    const float* __restrict__ xr, const float* __restrict__ xc,
    const float* __restrict__ Wx0, const float* __restrict__ Wh0, const float* __restrict__ b0,
    const float* __restrict__ Wx1, const float* __restrict__ Wh1, const float* __restrict__ b1,
    const float* __restrict__ Wd, const float* __restrict__ bd,
    float* __restrict__ out, float* ws)
{
  __shared__ __align__(16) unsigned char smem[SMEMB];
  const int bid = blockIdx.x;
  const int grp = bid >> 5, j = bid & 31;
  unsigned char* fg = (unsigned char*)ws + grp * FLG_G;
  unsigned char* f0 = fg;
  unsigned char* f1 = fg + F1B;
  unsigned char* fD = fg + FDB;
  _Float16* h0buf = (_Float16*)((char*)ws + RING_OFF);    // [NG][4][SLOT]
  _Float16* h1buf = h0buf + NG * 4 * SLOT;
  _Float16* h0g = h0buf + grp * 4 * SLOT;
  _Float16* h1g = h1buf + grp * 4 * SLOT;
  if (j < N0)            run_l0(j, grp, xr, xc, Wx0, Wh0, b0, h0g, f0, f1, smem);
  else if (j < N0 + N1)  run_l1(j - N0, grp, Wx1, Wh1, b1, h0g, h1g, f0, f1, fD, smem);
  else                   run_dense(grp, Wd, bd, h1g, out, f1, fD, smem);
}

extern "C" void kernel_launch(void* const* d_in, const int* in_sizes, int n_in,
                              void* d_out, int out_size, void* d_ws, size_t ws_size,
                              hipStream_t stream) {
  const float* xr  = (const float*)d_in[0];
  const float* xc  = (const float*)d_in[1];
  const float* Wx0 = (const float*)d_in[2];
  const float* Wh0 = (const float*)d_in[3];
  const float* b0  = (const float*)d_in[4];
  const float* Wx1 = (const float*)d_in[5];
  const float* Wh1 = (const float*)d_in[6];
  const float* b1  = (const float*)d_in[7];
  const float* Wd  = (const float*)d_in[8];
  const float* bd  = (const float*)d_in[9];
  float* out = (float*)d_out;
  float* ws  = (float*)d_ws;

  // zero byte flags + both h rings (re-zeroed every launch -> deterministic replays)
  hipMemsetAsync(d_ws, 0, WS_TOTAL, stream);
  hipLaunchKernelGGL(rnn_kernel, dim3(NBLK), dim3(NTHR), 0, stream,
                     xr, xc, Wx0, Wh0, b0, Wx1, Wh1, b1, Wd, bd, out, ws);
}